// Round 1
// baseline (937.819 us; speedup 1.0000x reference)
//
#include <hip/hip_runtime.h>
#include <cstdint>
#include <cstddef>

#define RN 200000   // nodes per side (NU == NI)
#define DIM 64
#define NE 1000000  // edges per relation

typedef __attribute__((ext_vector_type(8))) short short8v;   // 8 x bf16 fragment (4 VGPR)
typedef __attribute__((ext_vector_type(4))) float f32x4;
typedef __attribute__((ext_vector_type(8))) unsigned short us8;

struct Ptrs16 { const void* p[16]; };

__device__ __forceinline__ float bf2f(unsigned short u){
  unsigned int x = ((unsigned int)u) << 16;
  return __builtin_bit_cast(float, x);
}
__device__ __forceinline__ unsigned short f2bf(float f){
  unsigned int x = __builtin_bit_cast(unsigned int, f);
  unsigned int r = x + 0x7fffu + ((x >> 16) & 1u);   // RNE (values are finite/sane here)
  return (unsigned short)(r >> 16);
}

// ---- dtype sniffing: flags[0]=1 if floats are bf16, flags[1]=1 if indices are int64 ----
__global__ __launch_bounds__(256) void detect_k(const unsigned short* emb,
                                                const unsigned int* esrc,
                                                int* flags){
  __shared__ int cnt0, cnt1;
  int t = threadIdx.x;
  if (t == 0){ cnt0 = 0; cnt1 = 0; }
  __syncthreads();
  int c0 = 0, c1 = 0;
  #pragma unroll
  for (int s = 0; s < 4; ++s){
    int i = (t*4 + s) * 14;                 // even uint16 index
    float af = fabsf(bf2f(emb[i]));
    if (af > 0.0009765625f && af < 32.0f) c0++;
    int e = t*4 + s;
    if (esrc[2*e + 1] != 0u) c1++;          // int64 high words are 0
  }
  atomicAdd(&cnt0, c0); atomicAdd(&cnt1, c1);
  __syncthreads();
  if (t == 0){
    flags[0] = (cnt0 > 512) ? 1 : 0;
    flags[1] = (cnt1 < 512) ? 1 : 0;
  }
}

__global__ __launch_bounds__(256) void zero_k(int* p, int n){
  int i = blockIdx.x*256 + threadIdx.x;
  if (i < n) p[i] = 0;
}

// ---- canonicalize the 16 small param arrays (inputs 2..17) to fp32 ----
__global__ __launch_bounds__(256) void conv_params_k(Ptrs16 ps, const int* flags, float* out){
  const int offs[17] = {0,12288,12352,24640,24704,36992,37056,49344,49408,49472,
                        49536,49600,49664,49728,49792,49856,49920};
  int i = blockIdx.x*256 + threadIdx.x;
  if (i >= 49920) return;
  int a = 0;
  while (i >= offs[a+1]) ++a;
  int j = i - offs[a];
  float v = flags[0] ? bf2f(((const unsigned short*)ps.p[a])[j])
                     : ((const float*)ps.p[a])[j];
  out[i] = v;
}

// ---- canonicalize embeddings to internal bf16 ----
__global__ __launch_bounds__(256) void conv_emb_k(const void* in, unsigned short* out,
                                                  const int* flags, int n8){
  int i = blockIdx.x*256 + threadIdx.x;
  if (i >= n8) return;
  us8 o;
  if (flags[0]){
    o = ((const us8*)in)[i];
  } else {
    const float* f = (const float*)in + (size_t)i*8;
    #pragma unroll
    for (int r = 0; r < 8; ++r) o[r] = f2bf(f[r]);
  }
  ((us8*)out)[i] = o;
}

// ---- CSR build ----
__global__ __launch_bounds__(256) void count_k(const unsigned int* dst, int* cnt, const int* flags){
  int e = blockIdx.x*256 + threadIdx.x;
  if (e >= NE) return;
  int d = flags[1] ? (int)dst[2*e] : (int)dst[e];
  atomicAdd(&cnt[d], 1);
}

__global__ __launch_bounds__(256) void scanA_k(const int* cnt, int* bsum){
  __shared__ int sh[256];
  int b = blockIdx.x, t = threadIdx.x, i = b*256 + t;
  sh[t] = (i < RN) ? cnt[i] : 0;
  __syncthreads();
  for (int o = 128; o > 0; o >>= 1){
    if (t < o) sh[t] += sh[t+o];
    __syncthreads();
  }
  if (t == 0) bsum[b] = sh[0];
}

__global__ __launch_bounds__(1024) void scanB_k(int* bsum, int nb, int* rs){
  __shared__ int sh[1024];
  int t = threadIdx.x;
  int v = (t < nb) ? bsum[t] : 0;
  sh[t] = v;
  __syncthreads();
  for (int o = 1; o < 1024; o <<= 1){
    int x = (t >= o) ? sh[t-o] : 0;
    __syncthreads();
    sh[t] += x;
    __syncthreads();
  }
  if (t < nb) bsum[t] = sh[t];          // inclusive block sums
  if (t == nb-1) rs[RN] = sh[t];        // total == NE
}

__global__ __launch_bounds__(256) void scanC_k(const int* cnt, const int* bsum,
                                               int* rs, int* cur){   // cnt may alias cur
  __shared__ int sh[256];
  int b = blockIdx.x, t = threadIdx.x, i = b*256 + t;
  int v = (i < RN) ? cnt[i] : 0;
  sh[t] = v;
  __syncthreads();
  for (int o = 1; o < 256; o <<= 1){
    int x = (t >= o) ? sh[t-o] : 0;
    __syncthreads();
    sh[t] += x;
    __syncthreads();
  }
  if (i < RN){
    int start = (b > 0 ? bsum[b-1] : 0) + sh[t] - v;
    rs[i] = start;
    cur[i] = start;
  }
}

__global__ __launch_bounds__(256) void fill_k(const unsigned int* src, const unsigned int* dst,
                                              int* cur, int* col, const int* flags){
  int e = blockIdx.x*256 + threadIdx.x;
  if (e >= NE) return;
  int i64 = flags[1];
  int d = i64 ? (int)dst[2*e] : (int)dst[e];
  int s = i64 ? (int)src[2*e] : (int)src[e];
  int pos = atomicAdd(&cur[d], 1);
  col[pos] = s;
}

// ---- SpMM: one wave per dst row; agg = deg^-1/2 * sum_src X[src] (bf16 out) ----
__global__ __launch_bounds__(256) void spmm_k(const int* __restrict__ rs, const int* __restrict__ col,
                                              const unsigned short* __restrict__ X,
                                              unsigned short* __restrict__ agg){
  int w = (int)((blockIdx.x*256 + threadIdx.x) >> 6);
  int lane = threadIdx.x & 63;
  if (w >= RN) return;
  int b = rs[w], e = rs[w+1];
  float acc = 0.0f;
  for (int i = b; i < e; ++i){
    int s = col[i];
    acc += bf2f(X[(size_t)s*DIM + lane]);
  }
  int dg = e - b;
  float nrm = dg > 0 ? rsqrtf((float)dg) : 1.0f;
  agg[(size_t)w*DIM + lane] = f2bf(acc * nrm);
}

// ---- GEMM: H = Xd@W[0:64] + Ag@W[64:128] + b, bf16 out (maybe in-place into Ag),
//      fused BN sum/sumsq stats. Wave tile = 16 rows x 64 cols, mfma 16x16x32 bf16. ----
__global__ __launch_bounds__(256) void gemm_k(const unsigned short* __restrict__ Xd,
                                              const unsigned short* Ag,           // may alias Hout
                                              const float* __restrict__ W,
                                              const float* __restrict__ bias,
                                              unsigned short* Hout,
                                              float* __restrict__ stats){
  __shared__ float ls[128];
  for (int t0 = threadIdx.x; t0 < 128; t0 += 256) ls[t0] = 0.0f;
  __syncthreads();
  int lane = threadIdx.x & 63;
  int gw = (int)((blockIdx.x*256 + threadIdx.x) >> 6);
  int nw = (int)(gridDim.x * 4);
  int c16 = lane & 15, kg = lane >> 4;

  // B fragments for all 4 col-tiles x K=128 (built once per wave; W is tiny & cached)
  short8v Bf[2][2][4];
  #pragma unroll
  for (int s = 0; s < 2; ++s)
    #pragma unroll
    for (int t = 0; t < 2; ++t)
      #pragma unroll
      for (int c = 0; c < 4; ++c){
        short8v f;
        #pragma unroll
        for (int r = 0; r < 8; ++r){
          int k = s*64 + t*32 + kg*8 + r;
          f[r] = (short)f2bf(W[k*DIM + c*16 + c16]);
        }
        Bf[s][t][c] = f;
      }
  float bc[4];
  #pragma unroll
  for (int c = 0; c < 4; ++c) bc[c] = bias[c*16 + c16];

  float ssum[4] = {0,0,0,0}, ssq[4] = {0,0,0,0};
  const int ntile = RN/16;
  for (int tile = gw; tile < ntile; tile += nw){
    int r0 = tile*16;
    int ar = r0 + c16;                               // A row for this lane
    short8v A00 = ((const short8v*)Xd)[ar*8 + kg];       // k 0..31
    short8v A01 = ((const short8v*)Xd)[ar*8 + 4 + kg];   // k 32..63
    short8v A10 = ((const short8v*)Ag)[ar*8 + kg];
    short8v A11 = ((const short8v*)Ag)[ar*8 + 4 + kg];
    f32x4 acc[4];
    #pragma unroll
    for (int c = 0; c < 4; ++c){ f32x4 z = {bc[c],bc[c],bc[c],bc[c]}; acc[c] = z; }
    #pragma unroll
    for (int c = 0; c < 4; ++c){
      acc[c] = __builtin_amdgcn_mfma_f32_16x16x32_bf16(A00, Bf[0][0][c], acc[c], 0, 0, 0);
      acc[c] = __builtin_amdgcn_mfma_f32_16x16x32_bf16(A01, Bf[0][1][c], acc[c], 0, 0, 0);
      acc[c] = __builtin_amdgcn_mfma_f32_16x16x32_bf16(A10, Bf[1][0][c], acc[c], 0, 0, 0);
      acc[c] = __builtin_amdgcn_mfma_f32_16x16x32_bf16(A11, Bf[1][1][c], acc[c], 0, 0, 0);
    }
    int orow = r0 + kg*4;   // C layout: col = lane&15, row = (lane>>4)*4 + reg  [m89-verified]
    #pragma unroll
    for (int c = 0; c < 4; ++c)
      #pragma unroll
      for (int r = 0; r < 4; ++r){
        float v = acc[c][r];
        ssum[c] += v; ssq[c] += v*v;
        Hout[(size_t)(orow + r)*DIM + c*16 + c16] = f2bf(v);
      }
  }
  #pragma unroll
  for (int c = 0; c < 4; ++c){
    atomicAdd(&ls[c*16 + c16], ssum[c]);
    atomicAdd(&ls[64 + c*16 + c16], ssq[c]);
  }
  __syncthreads();
  for (int t0 = threadIdx.x; t0 < 128; t0 += 256) atomicAdd(&stats[t0], ls[t0]);
}

// ---- BN finalize: a = g*rsqrt(var+eps), c = be - mu*a ----
__global__ __launch_bounds__(64) void bnfin_k(const float* stats, const float* g,
                                              const float* be, float* ac){
  int j = threadIdx.x;
  if (j >= 64) return;
  float mu  = stats[j]    * (1.0f/RN);
  float var = stats[64+j] * (1.0f/RN) - mu*mu;
  float inv = rsqrtf(var + 1e-5f);
  float a = g[j] * inv;
  ac[j] = a;
  ac[64+j] = be[j] - mu*a;
}

// ---- BN + SiLU, in-place on internal bf16 buffer (layer 1) ----
__global__ __launch_bounds__(256) void bnapply_k(unsigned short* H, const float* __restrict__ ac, int n8){
  int i = blockIdx.x*256 + threadIdx.x;
  if (i >= n8) return;
  us8 v = ((us8*)H)[i];
  int cb = (i*8) & 63;
  #pragma unroll
  for (int r = 0; r < 8; ++r){
    float x = bf2f(v[r]);
    float y = ac[cb+r]*x + ac[64+cb+r];
    float o = y / (1.0f + expf(-y));
    v[r] = f2bf(o);
  }
  ((us8*)H)[i] = v;
}

// ---- BN + SiLU to d_out (dtype per flag) ----
__global__ __launch_bounds__(256) void bnout_k(const unsigned short* __restrict__ H,
                                               const float* __restrict__ ac,
                                               void* out, long long ooff,
                                               const int* __restrict__ flags, int n8){
  int i = blockIdx.x*256 + threadIdx.x;
  if (i >= n8) return;
  us8 v = ((const us8*)H)[i];
  int cb = (i*8) & 63;
  float o[8];
  #pragma unroll
  for (int r = 0; r < 8; ++r){
    float x = bf2f(v[r]);
    float y = ac[cb+r]*x + ac[64+cb+r];
    o[r] = y / (1.0f + expf(-y));
  }
  if (flags[0]){
    unsigned short* ob = (unsigned short*)out + ooff + (long long)i*8;
    us8 w;
    #pragma unroll
    for (int r = 0; r < 8; ++r) w[r] = f2bf(o[r]);
    *(us8*)ob = w;
  } else {
    float* ob = (float*)out + ooff + (long long)i*8;
    f32x4 w0 = {o[0],o[1],o[2],o[3]}, w1 = {o[4],o[5],o[6],o[7]};
    *(f32x4*)ob = w0;
    *((f32x4*)ob + 1) = w1;
  }
}

extern "C" void kernel_launch(void* const* d_in, const int* in_sizes, int n_in,
                              void* d_out, int out_size, void* d_ws, size_t ws_size,
                              hipStream_t stream){
  (void)in_sizes; (void)n_in; (void)out_size;
  const void* user_emb = d_in[0];
  const void* item_emb = d_in[1];
  const void* go_src   = d_in[18];
  const void* go_dst   = d_in[19];
  const void* back_src = d_in[20];
  const void* back_dst = d_in[21];

  char* ws = (char*)d_ws;
  size_t off = 0;
  auto alloc = [&](size_t bytes) -> void* {
    void* p = ws + off;
    off += (bytes + 255) & ~((size_t)255);
    return p;
  };
  int*   flags  = (int*)  alloc(64);
  float* params = (float*)alloc((size_t)49920*4);
  float* stats  = (float*)alloc(512*4);
  float* bnac   = (float*)alloc(512*4);
  int*   bsum   = (int*)  alloc(1024*4);
  int*   rs_go  = (int*)  alloc((size_t)(RN+1)*4);
  int*   rs_bk  = (int*)  alloc((size_t)(RN+1)*4);
  int*   cur    = (int*)  alloc((size_t)RN*4);
  int*   col_go = (int*)  alloc((size_t)NE*4);
  int*   col_bk = (int*)  alloc((size_t)NE*4);
  unsigned short* user_bf = (unsigned short*)alloc((size_t)RN*DIM*2);
  unsigned short* item_bf = (unsigned short*)alloc((size_t)RN*DIM*2);
  unsigned short* x2u     = (unsigned short*)alloc((size_t)RN*DIM*2);
  unsigned short* x2i     = (unsigned short*)alloc((size_t)RN*DIM*2);
  unsigned short* agg     = (unsigned short*)alloc((size_t)RN*DIM*2);
  if (off > ws_size) return;  // ws too small: leave output wrong -> visible as absmax == 5.8125

  const int GE = (NE + 255)/256;        // 3907
  const int GR = (RN + 255)/256;        // 782
  const int G8 = (RN*DIM/8)/256;        // 6250
  const int GS = RN*64/256;             // 50000: one wave per row

  float* W_go1 = params + 0;     float* b_go1 = params + 12288;
  float* W_bk1 = params + 12352; float* b_bk1 = params + 24640;
  float* W_go2 = params + 24704; float* b_go2 = params + 36992;
  float* W_bk2 = params + 37056; float* b_bk2 = params + 49344;
  float* g1u = params + 49408; float* be1u = params + 49472;
  float* g1i = params + 49536; float* be1i = params + 49600;
  float* g2u = params + 49664; float* be2u = params + 49728;
  float* g2i = params + 49792; float* be2i = params + 49856;

  detect_k<<<1,256,0,stream>>>((const unsigned short*)user_emb, (const unsigned int*)go_src, flags);
  zero_k<<<2,256,0,stream>>>((int*)stats, 512);
  Ptrs16 ps;
  for (int i = 0; i < 16; ++i) ps.p[i] = d_in[2+i];
  conv_params_k<<<196,256,0,stream>>>(ps, flags, params);
  conv_emb_k<<<G8,256,0,stream>>>(user_emb, user_bf, flags, RN*DIM/8);
  conv_emb_k<<<G8,256,0,stream>>>(item_emb, item_bf, flags, RN*DIM/8);

  // CSR go (dst = items, src = users)
  zero_k<<<GR,256,0,stream>>>(cur, RN);
  count_k<<<GE,256,0,stream>>>((const unsigned int*)go_dst, cur, flags);
  scanA_k<<<GR,256,0,stream>>>(cur, bsum);
  scanB_k<<<1,1024,0,stream>>>(bsum, GR, rs_go);
  scanC_k<<<GR,256,0,stream>>>(cur, bsum, rs_go, cur);
  fill_k<<<GE,256,0,stream>>>((const unsigned int*)go_src, (const unsigned int*)go_dst, cur, col_go, flags);

  // CSR back (dst = users, src = items)
  zero_k<<<GR,256,0,stream>>>(cur, RN);
  count_k<<<GE,256,0,stream>>>((const unsigned int*)back_dst, cur, flags);
  scanA_k<<<GR,256,0,stream>>>(cur, bsum);
  scanB_k<<<1,1024,0,stream>>>(bsum, GR, rs_bk);
  scanC_k<<<GR,256,0,stream>>>(cur, bsum, rs_bk, cur);
  fill_k<<<GE,256,0,stream>>>((const unsigned int*)back_src, (const unsigned int*)back_dst, cur, col_bk, flags);

  // ---- layer 1 ----
  spmm_k<<<GS,256,0,stream>>>(rs_go, col_go, user_bf, agg);
  gemm_k<<<1024,256,0,stream>>>(item_bf, agg, W_go1, b_go1, x2i, stats + 0);
  bnfin_k<<<1,64,0,stream>>>(stats + 0, g1i, be1i, bnac + 0);
  bnapply_k<<<G8,256,0,stream>>>(x2i, bnac + 0, RN*DIM/8);

  spmm_k<<<GS,256,0,stream>>>(rs_bk, col_bk, item_bf, agg);
  gemm_k<<<1024,256,0,stream>>>(user_bf, agg, W_bk1, b_bk1, x2u, stats + 128);
  bnfin_k<<<1,64,0,stream>>>(stats + 128, g1u, be1u, bnac + 128);
  bnapply_k<<<G8,256,0,stream>>>(x2u, bnac + 128, RN*DIM/8);

  // ---- layer 2 (GEMMs write in-place into agg; items first, then users) ----
  spmm_k<<<GS,256,0,stream>>>(rs_go, col_go, x2u, agg);
  gemm_k<<<1024,256,0,stream>>>(x2i, agg, W_go2, b_go2, agg, stats + 256);
  bnfin_k<<<1,64,0,stream>>>(stats + 256, g2i, be2i, bnac + 256);
  bnout_k<<<G8,256,0,stream>>>(agg, bnac + 256, d_out, (long long)RN*DIM, flags, RN*DIM/8);

  spmm_k<<<GS,256,0,stream>>>(rs_bk, col_bk, x2i, agg);
  gemm_k<<<1024,256,0,stream>>>(x2u, agg, W_bk2, b_bk2, agg, stats + 384);
  bnfin_k<<<1,64,0,stream>>>(stats + 384, g2u, be2u, bnac + 384);
  bnout_k<<<G8,256,0,stream>>>(agg, bnac + 384, d_out, 0LL, flags, RN*DIM/8);
}

// Round 2
// 719.223 us; speedup vs baseline: 1.3039x; 1.3039x over previous
//
#include <hip/hip_runtime.h>
#include <cstdint>
#include <cstddef>

#define RN 200000   // nodes per side (NU == NI)
#define DIM 64
#define NE 1000000  // edges per relation

typedef __attribute__((ext_vector_type(8))) short short8v;   // 8 x bf16 fragment (4 VGPR)
typedef __attribute__((ext_vector_type(4))) float f32x4;
typedef __attribute__((ext_vector_type(8))) unsigned short us8;

struct Ptrs16 { const void* p[16]; };

__device__ __forceinline__ float bf2f(unsigned short u){
  unsigned int x = ((unsigned int)u) << 16;
  return __builtin_bit_cast(float, x);
}
__device__ __forceinline__ unsigned short f2bf(float f){
  unsigned int x = __builtin_bit_cast(unsigned int, f);
  unsigned int r = x + 0x7fffu + ((x >> 16) & 1u);   // RNE (values are finite/sane here)
  return (unsigned short)(r >> 16);
}

// ---- dtype sniffing: flags[0]=1 if floats are bf16, flags[1]=1 if indices are int64 ----
__global__ __launch_bounds__(256) void detect_k(const unsigned short* emb,
                                                const unsigned int* esrc,
                                                int* flags){
  __shared__ int cnt0, cnt1;
  int t = threadIdx.x;
  if (t == 0){ cnt0 = 0; cnt1 = 0; }
  __syncthreads();
  int c0 = 0, c1 = 0;
  #pragma unroll
  for (int s = 0; s < 4; ++s){
    int i = (t*4 + s) * 14;                 // even uint16 index
    float af = fabsf(bf2f(emb[i]));
    if (af > 0.0009765625f && af < 32.0f) c0++;
    int e = t*4 + s;
    if (esrc[2*e + 1] != 0u) c1++;          // int64 high words are 0
  }
  atomicAdd(&cnt0, c0); atomicAdd(&cnt1, c1);
  __syncthreads();
  if (t == 0){
    flags[0] = (cnt0 > 512) ? 1 : 0;
    flags[1] = (cnt1 < 512) ? 1 : 0;
  }
}

__global__ __launch_bounds__(256) void zero_k(int* p, int n){
  int i = blockIdx.x*256 + threadIdx.x;
  if (i < n) p[i] = 0;
}

// ---- canonicalize the 16 small param arrays (inputs 2..17) to fp32 ----
__global__ __launch_bounds__(256) void conv_params_k(Ptrs16 ps, const int* flags, float* out){
  const int offs[17] = {0,12288,12352,24640,24704,36992,37056,49344,49408,49472,
                        49536,49600,49664,49728,49792,49856,49920};
  int i = blockIdx.x*256 + threadIdx.x;
  if (i >= 49920) return;
  int a = 0;
  while (i >= offs[a+1]) ++a;
  int j = i - offs[a];
  float v = flags[0] ? bf2f(((const unsigned short*)ps.p[a])[j])
                     : ((const float*)ps.p[a])[j];
  out[i] = v;
}

// ---- canonicalize embeddings to internal bf16 ----
__global__ __launch_bounds__(256) void conv_emb_k(const void* in, unsigned short* out,
                                                  const int* flags, int n8){
  int i = blockIdx.x*256 + threadIdx.x;
  if (i >= n8) return;
  us8 o;
  if (flags[0]){
    o = ((const us8*)in)[i];
  } else {
    const float* f = (const float*)in + (size_t)i*8;
    #pragma unroll
    for (int r = 0; r < 8; ++r) o[r] = f2bf(f[r]);
  }
  ((us8*)out)[i] = o;
}

// ---- CSR build ----
__global__ __launch_bounds__(256) void count_k(const unsigned int* dst, int* cnt, const int* flags){
  int e = blockIdx.x*256 + threadIdx.x;
  if (e >= NE) return;
  int d = flags[1] ? (int)dst[2*e] : (int)dst[e];
  atomicAdd(&cnt[d], 1);
}

__global__ __launch_bounds__(256) void scanA_k(const int* cnt, int* bsum){
  __shared__ int sh[256];
  int b = blockIdx.x, t = threadIdx.x, i = b*256 + t;
  sh[t] = (i < RN) ? cnt[i] : 0;
  __syncthreads();
  for (int o = 128; o > 0; o >>= 1){
    if (t < o) sh[t] += sh[t+o];
    __syncthreads();
  }
  if (t == 0) bsum[b] = sh[0];
}

__global__ __launch_bounds__(1024) void scanB_k(int* bsum, int nb, int* rs){
  __shared__ int sh[1024];
  int t = threadIdx.x;
  int v = (t < nb) ? bsum[t] : 0;
  sh[t] = v;
  __syncthreads();
  for (int o = 1; o < 1024; o <<= 1){
    int x = (t >= o) ? sh[t-o] : 0;
    __syncthreads();
    sh[t] += x;
    __syncthreads();
  }
  if (t < nb) bsum[t] = sh[t];          // inclusive block sums
  if (t == nb-1) rs[RN] = sh[t];        // total == NE
}

__global__ __launch_bounds__(256) void scanC_k(const int* cnt, const int* bsum,
                                               int* rs, int* cur){   // cnt may alias cur
  __shared__ int sh[256];
  int b = blockIdx.x, t = threadIdx.x, i = b*256 + t;
  int v = (i < RN) ? cnt[i] : 0;
  sh[t] = v;
  __syncthreads();
  for (int o = 1; o < 256; o <<= 1){
    int x = (t >= o) ? sh[t-o] : 0;
    __syncthreads();
    sh[t] += x;
    __syncthreads();
  }
  if (i < RN){
    int start = (b > 0 ? bsum[b-1] : 0) + sh[t] - v;
    rs[i] = start;
    cur[i] = start;
  }
}

__global__ __launch_bounds__(256) void fill_k(const unsigned int* src, const unsigned int* dst,
                                              int* cur, int* col, const int* flags){
  int e = blockIdx.x*256 + threadIdx.x;
  if (e >= NE) return;
  int i64 = flags[1];
  int d = i64 ? (int)dst[2*e] : (int)dst[e];
  int s = i64 ? (int)src[2*e] : (int)src[e];
  int pos = atomicAdd(&cur[d], 1);
  col[pos] = s;
}

// ---- SpMM: one wave per dst row; agg = deg^-1/2 * sum_src X[src] (bf16 out) ----
// Latency fix (R2): scalar row bounds via readfirstlane; batch 8 edge indices
// (tail clamped to idx0 BEFORE the gather -> no wild addresses), then 8
// INDEPENDENT row gathers in flight; uniform-predicate accumulate.
__global__ __launch_bounds__(256) void spmm_k(const int* __restrict__ rs, const int* __restrict__ col,
                                              const unsigned short* __restrict__ X,
                                              unsigned short* __restrict__ agg){
  int w = (int)((blockIdx.x*256 + threadIdx.x) >> 6);
  int lane = threadIdx.x & 63;
  if (w >= RN) return;
  int b = __builtin_amdgcn_readfirstlane(rs[w]);
  int e = __builtin_amdgcn_readfirstlane(rs[w+1]);
  float acc = 0.0f;
  for (int i = b; i < e; i += 8){
    int rem = e - i;                       // wave-uniform
    int idx0 = col[i];
    int idx[8];
    idx[0] = idx0;
    #pragma unroll
    for (int j = 1; j < 8; ++j)
      idx[j] = (j < rem) ? col[i + j] : idx0;   // clamp tail to a valid row
    float v[8];
    #pragma unroll
    for (int j = 0; j < 8; ++j)
      v[j] = bf2f(X[((size_t)(unsigned)idx[j] << 6) + lane]);
    #pragma unroll
    for (int j = 0; j < 8; ++j)
      acc += (j < rem) ? v[j] : 0.0f;
  }
  int dg = e - b;
  float nrm = dg > 0 ? rsqrtf((float)dg) : 1.0f;
  agg[((size_t)w << 6) + lane] = f2bf(acc * nrm);
}

// ---- GEMM: H = Xd@W[0:64] + Ag@W[64:128] + b, bf16 out (maybe in-place into Ag),
//      fused BN sum/sumsq stats. Wave tile = 16 rows x 64 cols, mfma 16x16x32 bf16. ----
__global__ __launch_bounds__(256) void gemm_k(const unsigned short* __restrict__ Xd,
                                              const unsigned short* Ag,           // may alias Hout
                                              const float* __restrict__ W,
                                              const float* __restrict__ bias,
                                              unsigned short* Hout,
                                              float* __restrict__ stats){
  __shared__ float ls[128];
  for (int t0 = threadIdx.x; t0 < 128; t0 += 256) ls[t0] = 0.0f;
  __syncthreads();
  int lane = threadIdx.x & 63;
  int gw = (int)((blockIdx.x*256 + threadIdx.x) >> 6);
  int nw = (int)(gridDim.x * 4);
  int c16 = lane & 15, kg = lane >> 4;

  // B fragments for all 4 col-tiles x K=128 (built once per wave; W is tiny & cached)
  short8v Bf[2][2][4];
  #pragma unroll
  for (int s = 0; s < 2; ++s)
    #pragma unroll
    for (int t = 0; t < 2; ++t)
      #pragma unroll
      for (int c = 0; c < 4; ++c){
        short8v f;
        #pragma unroll
        for (int r = 0; r < 8; ++r){
          int k = s*64 + t*32 + kg*8 + r;
          f[r] = (short)f2bf(W[k*DIM + c*16 + c16]);
        }
        Bf[s][t][c] = f;
      }
  float bc[4];
  #pragma unroll
  for (int c = 0; c < 4; ++c) bc[c] = bias[c*16 + c16];

  float ssum[4] = {0,0,0,0}, ssq[4] = {0,0,0,0};
  const int ntile = RN/16;
  for (int tile = gw; tile < ntile; tile += nw){
    int r0 = tile*16;
    int ar = r0 + c16;                               // A row for this lane
    short8v A00 = ((const short8v*)Xd)[ar*8 + kg];       // k 0..31
    short8v A01 = ((const short8v*)Xd)[ar*8 + 4 + kg];   // k 32..63
    short8v A10 = ((const short8v*)Ag)[ar*8 + kg];
    short8v A11 = ((const short8v*)Ag)[ar*8 + 4 + kg];
    f32x4 acc[4];
    #pragma unroll
    for (int c = 0; c < 4; ++c){ f32x4 z = {bc[c],bc[c],bc[c],bc[c]}; acc[c] = z; }
    #pragma unroll
    for (int c = 0; c < 4; ++c){
      acc[c] = __builtin_amdgcn_mfma_f32_16x16x32_bf16(A00, Bf[0][0][c], acc[c], 0, 0, 0);
      acc[c] = __builtin_amdgcn_mfma_f32_16x16x32_bf16(A01, Bf[0][1][c], acc[c], 0, 0, 0);
      acc[c] = __builtin_amdgcn_mfma_f32_16x16x32_bf16(A10, Bf[1][0][c], acc[c], 0, 0, 0);
      acc[c] = __builtin_amdgcn_mfma_f32_16x16x32_bf16(A11, Bf[1][1][c], acc[c], 0, 0, 0);
    }
    int orow = r0 + kg*4;   // C layout: col = lane&15, row = (lane>>4)*4 + reg  [m89-verified]
    #pragma unroll
    for (int c = 0; c < 4; ++c)
      #pragma unroll
      for (int r = 0; r < 4; ++r){
        float v = acc[c][r];
        ssum[c] += v; ssq[c] += v*v;
        Hout[(size_t)(orow + r)*DIM + c*16 + c16] = f2bf(v);
      }
  }
  #pragma unroll
  for (int c = 0; c < 4; ++c){
    atomicAdd(&ls[c*16 + c16], ssum[c]);
    atomicAdd(&ls[64 + c*16 + c16], ssq[c]);
  }
  __syncthreads();
  for (int t0 = threadIdx.x; t0 < 128; t0 += 256) atomicAdd(&stats[t0], ls[t0]);
}

// ---- BN finalize: a = g*rsqrt(var+eps), c = be - mu*a ----
__global__ __launch_bounds__(64) void bnfin_k(const float* stats, const float* g,
                                              const float* be, float* ac){
  int j = threadIdx.x;
  if (j >= 64) return;
  float mu  = stats[j]    * (1.0f/RN);
  float var = stats[64+j] * (1.0f/RN) - mu*mu;
  float inv = rsqrtf(var + 1e-5f);
  float a = g[j] * inv;
  ac[j] = a;
  ac[64+j] = be[j] - mu*a;
}

// ---- BN + SiLU, in-place on internal bf16 buffer (layer 1) ----
__global__ __launch_bounds__(256) void bnapply_k(unsigned short* H, const float* __restrict__ ac, int n8){
  int i = blockIdx.x*256 + threadIdx.x;
  if (i >= n8) return;
  us8 v = ((us8*)H)[i];
  int cb = (i*8) & 63;
  #pragma unroll
  for (int r = 0; r < 8; ++r){
    float x = bf2f(v[r]);
    float y = ac[cb+r]*x + ac[64+cb+r];
    float o = y / (1.0f + expf(-y));
    v[r] = f2bf(o);
  }
  ((us8*)H)[i] = v;
}

// ---- BN + SiLU to d_out (dtype per flag) ----
__global__ __launch_bounds__(256) void bnout_k(const unsigned short* __restrict__ H,
                                               const float* __restrict__ ac,
                                               void* out, long long ooff,
                                               const int* __restrict__ flags, int n8){
  int i = blockIdx.x*256 + threadIdx.x;
  if (i >= n8) return;
  us8 v = ((const us8*)H)[i];
  int cb = (i*8) & 63;
  float o[8];
  #pragma unroll
  for (int r = 0; r < 8; ++r){
    float x = bf2f(v[r]);
    float y = ac[cb+r]*x + ac[64+cb+r];
    o[r] = y / (1.0f + expf(-y));
  }
  if (flags[0]){
    unsigned short* ob = (unsigned short*)out + ooff + (long long)i*8;
    us8 w;
    #pragma unroll
    for (int r = 0; r < 8; ++r) w[r] = f2bf(o[r]);
    *(us8*)ob = w;
  } else {
    float* ob = (float*)out + ooff + (long long)i*8;
    f32x4 w0 = {o[0],o[1],o[2],o[3]}, w1 = {o[4],o[5],o[6],o[7]};
    *(f32x4*)ob = w0;
    *((f32x4*)ob + 1) = w1;
  }
}

extern "C" void kernel_launch(void* const* d_in, const int* in_sizes, int n_in,
                              void* d_out, int out_size, void* d_ws, size_t ws_size,
                              hipStream_t stream){
  (void)in_sizes; (void)n_in; (void)out_size;
  const void* user_emb = d_in[0];
  const void* item_emb = d_in[1];
  const void* go_src   = d_in[18];
  const void* go_dst   = d_in[19];
  const void* back_src = d_in[20];
  const void* back_dst = d_in[21];

  char* ws = (char*)d_ws;
  size_t off = 0;
  auto alloc = [&](size_t bytes) -> void* {
    void* p = ws + off;
    off += (bytes + 255) & ~((size_t)255);
    return p;
  };
  int*   flags  = (int*)  alloc(64);
  float* params = (float*)alloc((size_t)49920*4);
  float* stats  = (float*)alloc(512*4);
  float* bnac   = (float*)alloc(512*4);
  int*   bsum   = (int*)  alloc(1024*4);
  int*   rs_go  = (int*)  alloc((size_t)(RN+1)*4);
  int*   rs_bk  = (int*)  alloc((size_t)(RN+1)*4);
  int*   cur    = (int*)  alloc((size_t)RN*4);
  int*   col_go = (int*)  alloc((size_t)NE*4);
  int*   col_bk = (int*)  alloc((size_t)NE*4);
  unsigned short* user_bf = (unsigned short*)alloc((size_t)RN*DIM*2);
  unsigned short* item_bf = (unsigned short*)alloc((size_t)RN*DIM*2);
  unsigned short* x2u     = (unsigned short*)alloc((size_t)RN*DIM*2);
  unsigned short* x2i     = (unsigned short*)alloc((size_t)RN*DIM*2);
  unsigned short* agg     = (unsigned short*)alloc((size_t)RN*DIM*2);
  if (off > ws_size) return;  // ws too small: leave output wrong -> visible as absmax == 5.8125

  const int GE = (NE + 255)/256;        // 3907
  const int GR = (RN + 255)/256;        // 782
  const int G8 = (RN*DIM/8)/256;        // 6250
  const int GS = RN*64/256;             // 50000: one wave per row

  float* W_go1 = params + 0;     float* b_go1 = params + 12288;
  float* W_bk1 = params + 12352; float* b_bk1 = params + 24640;
  float* W_go2 = params + 24704; float* b_go2 = params + 36992;
  float* W_bk2 = params + 37056; float* b_bk2 = params + 49344;
  float* g1u = params + 49408; float* be1u = params + 49472;
  float* g1i = params + 49536; float* be1i = params + 49600;
  float* g2u = params + 49664; float* be2u = params + 49728;
  float* g2i = params + 49792; float* be2i = params + 49856;

  detect_k<<<1,256,0,stream>>>((const unsigned short*)user_emb, (const unsigned int*)go_src, flags);
  zero_k<<<2,256,0,stream>>>((int*)stats, 512);
  Ptrs16 ps;
  for (int i = 0; i < 16; ++i) ps.p[i] = d_in[2+i];
  conv_params_k<<<196,256,0,stream>>>(ps, flags, params);
  conv_emb_k<<<G8,256,0,stream>>>(user_emb, user_bf, flags, RN*DIM/8);
  conv_emb_k<<<G8,256,0,stream>>>(item_emb, item_bf, flags, RN*DIM/8);

  // CSR go (dst = items, src = users)
  zero_k<<<GR,256,0,stream>>>(cur, RN);
  count_k<<<GE,256,0,stream>>>((const unsigned int*)go_dst, cur, flags);
  scanA_k<<<GR,256,0,stream>>>(cur, bsum);
  scanB_k<<<1,1024,0,stream>>>(bsum, GR, rs_go);
  scanC_k<<<GR,256,0,stream>>>(cur, bsum, rs_go, cur);
  fill_k<<<GE,256,0,stream>>>((const unsigned int*)go_src, (const unsigned int*)go_dst, cur, col_go, flags);

  // CSR back (dst = users, src = items)
  zero_k<<<GR,256,0,stream>>>(cur, RN);
  count_k<<<GE,256,0,stream>>>((const unsigned int*)back_dst, cur, flags);
  scanA_k<<<GR,256,0,stream>>>(cur, bsum);
  scanB_k<<<1,1024,0,stream>>>(bsum, GR, rs_bk);
  scanC_k<<<GR,256,0,stream>>>(cur, bsum, rs_bk, cur);
  fill_k<<<GE,256,0,stream>>>((const unsigned int*)back_src, (const unsigned int*)back_dst, cur, col_bk, flags);

  // ---- layer 1 ----
  spmm_k<<<GS,256,0,stream>>>(rs_go, col_go, user_bf, agg);
  gemm_k<<<1024,256,0,stream>>>(item_bf, agg, W_go1, b_go1, x2i, stats + 0);
  bnfin_k<<<1,64,0,stream>>>(stats + 0, g1i, be1i, bnac + 0);
  bnapply_k<<<G8,256,0,stream>>>(x2i, bnac + 0, RN*DIM/8);

  spmm_k<<<GS,256,0,stream>>>(rs_bk, col_bk, item_bf, agg);
  gemm_k<<<1024,256,0,stream>>>(user_bf, agg, W_bk1, b_bk1, x2u, stats + 128);
  bnfin_k<<<1,64,0,stream>>>(stats + 128, g1u, be1u, bnac + 128);
  bnapply_k<<<G8,256,0,stream>>>(x2u, bnac + 128, RN*DIM/8);

  // ---- layer 2 (GEMMs write in-place into agg; items first, then users) ----
  spmm_k<<<GS,256,0,stream>>>(rs_go, col_go, x2u, agg);
  gemm_k<<<1024,256,0,stream>>>(x2i, agg, W_go2, b_go2, agg, stats + 256);
  bnfin_k<<<1,64,0,stream>>>(stats + 256, g2i, be2i, bnac + 256);
  bnout_k<<<G8,256,0,stream>>>(agg, bnac + 256, d_out, (long long)RN*DIM, flags, RN*DIM/8);

  spmm_k<<<GS,256,0,stream>>>(rs_bk, col_bk, x2i, agg);
  gemm_k<<<1024,256,0,stream>>>(x2u, agg, W_bk2, b_bk2, agg, stats + 384);
  bnfin_k<<<1,64,0,stream>>>(stats + 384, g2u, be2u, bnac + 384);
  bnout_k<<<G8,256,0,stream>>>(agg, bnac + 384, d_out, 0LL, flags, RN*DIM/8);
}

// Round 3
// 709.206 us; speedup vs baseline: 1.3224x; 1.0141x over previous
//
#include <hip/hip_runtime.h>
#include <cstdint>
#include <cstddef>

#define RN 200000   // nodes per side (NU == NI)
#define NR2 400000  // both sides
#define DIM 64
#define NE 1000000  // edges per relation

typedef __attribute__((ext_vector_type(8))) short short8v;   // 8 x bf16 fragment (4 VGPR)
typedef __attribute__((ext_vector_type(4))) float f32x4;
typedef __attribute__((ext_vector_type(8))) unsigned short us8;

struct Ptrs16 { const void* p[16]; };

__device__ __forceinline__ float bf2f(unsigned short u){
  unsigned int x = ((unsigned int)u) << 16;
  return __builtin_bit_cast(float, x);
}
__device__ __forceinline__ unsigned short f2bf(float f){
  unsigned int x = __builtin_bit_cast(unsigned int, f);
  unsigned int r = x + 0x7fffu + ((x >> 16) & 1u);   // RNE (values are finite/sane here)
  return (unsigned short)(r >> 16);
}

// ---- dtype sniffing: flags[0]=1 if floats are bf16, flags[1]=1 if indices are int64 ----
__global__ __launch_bounds__(256) void detect_k(const unsigned short* emb,
                                                const unsigned int* esrc,
                                                int* flags){
  __shared__ int cnt0, cnt1;
  int t = threadIdx.x;
  if (t == 0){ cnt0 = 0; cnt1 = 0; }
  __syncthreads();
  int c0 = 0, c1 = 0;
  #pragma unroll
  for (int s = 0; s < 4; ++s){
    int i = (t*4 + s) * 14;                 // even uint16 index
    float af = fabsf(bf2f(emb[i]));
    if (af > 0.0009765625f && af < 32.0f) c0++;
    int e = t*4 + s;
    if (esrc[2*e + 1] != 0u) c1++;          // int64 high words are 0
  }
  atomicAdd(&cnt0, c0); atomicAdd(&cnt1, c1);
  __syncthreads();
  if (t == 0){
    flags[0] = (cnt0 > 512) ? 1 : 0;
    flags[1] = (cnt1 < 512) ? 1 : 0;
  }
}

__global__ __launch_bounds__(256) void zero_k(int* p, int n){
  int i = blockIdx.x*256 + threadIdx.x;
  if (i < n) p[i] = 0;
}

// ---- canonicalize the 16 small param arrays (inputs 2..17) to fp32 ----
__global__ __launch_bounds__(256) void conv_params_k(Ptrs16 ps, const int* flags, float* out){
  const int offs[17] = {0,12288,12352,24640,24704,36992,37056,49344,49408,49472,
                        49536,49600,49664,49728,49792,49856,49920};
  int i = blockIdx.x*256 + threadIdx.x;
  if (i >= 49920) return;
  int a = 0;
  while (i >= offs[a+1]) ++a;
  int j = i - offs[a];
  float v = flags[0] ? bf2f(((const unsigned short*)ps.p[a])[j])
                     : ((const float*)ps.p[a])[j];
  out[i] = v;
}

// ---- canonicalize embeddings to internal bf16 ----
__global__ __launch_bounds__(256) void conv_emb_k(const void* in, unsigned short* out,
                                                  const int* flags, int n8){
  int i = blockIdx.x*256 + threadIdx.x;
  if (i >= n8) return;
  us8 o;
  if (flags[0]){
    o = ((const us8*)in)[i];
  } else {
    const float* f = (const float*)in + (size_t)i*8;
    #pragma unroll
    for (int r = 0; r < 8; ++r) o[r] = f2bf(f[r]);
  }
  ((us8*)out)[i] = o;
}

// ---- CSR build: both relations in one pass; counts live in cur2[0..NR2) ----
__global__ __launch_bounds__(256) void count2_k(const unsigned int* go_dst,
                                                const unsigned int* back_dst,
                                                int* cnt, const int* flags){
  int e = blockIdx.x*256 + threadIdx.x;
  if (e >= NE) return;
  int i64 = flags[1];
  int d0 = i64 ? (int)__builtin_nontemporal_load(&go_dst[2*e])   : (int)__builtin_nontemporal_load(&go_dst[e]);
  int d1 = i64 ? (int)__builtin_nontemporal_load(&back_dst[2*e]) : (int)__builtin_nontemporal_load(&back_dst[e]);
  atomicAdd(&cnt[d0], 1);
  atomicAdd(&cnt[RN + d1], 1);
}

// scan over NR2 elements, 512-thread blocks (782 blocks -> scanB fits 1024)
__global__ __launch_bounds__(512) void scanA_k(const int* cnt, int* bsum){
  __shared__ int sh[512];
  int b = blockIdx.x, t = threadIdx.x, i = b*512 + t;
  sh[t] = (i < NR2) ? cnt[i] : 0;
  __syncthreads();
  for (int o = 256; o > 0; o >>= 1){
    if (t < o) sh[t] += sh[t+o];
    __syncthreads();
  }
  if (t == 0) bsum[b] = sh[0];
}

__global__ __launch_bounds__(1024) void scanB_k(int* bsum, int nb, int* rs){
  __shared__ int sh[1024];
  int t = threadIdx.x;
  int v = (t < nb) ? bsum[t] : 0;
  sh[t] = v;
  __syncthreads();
  for (int o = 1; o < 1024; o <<= 1){
    int x = (t >= o) ? sh[t-o] : 0;
    __syncthreads();
    sh[t] += x;
    __syncthreads();
  }
  if (t < nb) bsum[t] = sh[t];          // inclusive block sums
  if (t == nb-1) rs[NR2] = sh[t];       // total == 2*NE
}

__global__ __launch_bounds__(512) void scanC_k(const int* cnt, const int* bsum,
                                               int* rs, int* cur){   // cnt aliases cur
  __shared__ int sh[512];
  int b = blockIdx.x, t = threadIdx.x, i = b*512 + t;
  int v = (i < NR2) ? cnt[i] : 0;
  sh[t] = v;
  __syncthreads();
  for (int o = 1; o < 512; o <<= 1){
    int x = (t >= o) ? sh[t-o] : 0;
    __syncthreads();
    sh[t] += x;
    __syncthreads();
  }
  if (i < NR2){
    int start = (b > 0 ? bsum[b-1] : 0) + sh[t] - v;
    rs[i] = start;
    cur[i] = start;
  }
}

// both relations; col scatter uses NT stores (no L2 allocate -> merge in L3,
// kills the ~17x partial-line writeback amplification seen in R2)
__global__ __launch_bounds__(256) void fill2_k(const unsigned int* go_src, const unsigned int* go_dst,
                                               const unsigned int* back_src, const unsigned int* back_dst,
                                               int* cur, int* col, const int* flags){
  int e = blockIdx.x*256 + threadIdx.x;
  if (e >= NE) return;
  int i64 = flags[1];
  int d0 = i64 ? (int)__builtin_nontemporal_load(&go_dst[2*e])   : (int)__builtin_nontemporal_load(&go_dst[e]);
  int s0 = i64 ? (int)__builtin_nontemporal_load(&go_src[2*e])   : (int)__builtin_nontemporal_load(&go_src[e]);
  int d1 = i64 ? (int)__builtin_nontemporal_load(&back_dst[2*e]) : (int)__builtin_nontemporal_load(&back_dst[e]);
  int s1 = i64 ? (int)__builtin_nontemporal_load(&back_src[2*e]) : (int)__builtin_nontemporal_load(&back_src[e]);
  int p0 = atomicAdd(&cur[d0], 1);
  __builtin_nontemporal_store(s0, &col[p0]);
  int p1 = atomicAdd(&cur[RN + d1], 1);
  __builtin_nontemporal_store(s1, &col[p1]);
}

// ---- SpMM: one wave per dst row; agg = deg^-1/2 * sum_src X[src] (bf16 out) ----
__global__ __launch_bounds__(256) void spmm_k(const int* __restrict__ rs, const int* __restrict__ col,
                                              const unsigned short* __restrict__ X,
                                              unsigned short* __restrict__ agg){
  int w = (int)((blockIdx.x*256 + threadIdx.x) >> 6);
  int lane = threadIdx.x & 63;
  if (w >= RN) return;
  int b = __builtin_amdgcn_readfirstlane(rs[w]);
  int e = __builtin_amdgcn_readfirstlane(rs[w+1]);
  float acc = 0.0f;
  for (int i = b; i < e; i += 8){
    int rem = e - i;                       // wave-uniform
    int idx0 = __builtin_nontemporal_load(&col[i]);
    int idx[8];
    idx[0] = idx0;
    #pragma unroll
    for (int j = 1; j < 8; ++j)
      idx[j] = (j < rem) ? __builtin_nontemporal_load(&col[i + j]) : idx0;  // clamp tail
    float v[8];
    #pragma unroll
    for (int j = 0; j < 8; ++j)
      v[j] = bf2f(X[((size_t)(unsigned)idx[j] << 6) + lane]);
    #pragma unroll
    for (int j = 0; j < 8; ++j)
      acc += (j < rem) ? v[j] : 0.0f;
  }
  int dg = e - b;
  float nrm = dg > 0 ? rsqrtf((float)dg) : 1.0f;
  __builtin_nontemporal_store(f2bf(acc * nrm), &agg[((size_t)w << 6) + lane]);
}

// ---- GEMM: H = Xd@W[0:64] + Ag@W[64:128] + b, bf16 out (maybe in-place into Ag),
//      fused BN sum/sumsq stats. Wave tile = 16 rows x 64 cols, mfma 16x16x32 bf16. ----
__global__ __launch_bounds__(256) void gemm_k(const unsigned short* __restrict__ Xd,
                                              const unsigned short* Ag,           // may alias Hout
                                              const float* __restrict__ W,
                                              const float* __restrict__ bias,
                                              unsigned short* Hout,
                                              float* __restrict__ stats){
  __shared__ float ls[128];
  for (int t0 = threadIdx.x; t0 < 128; t0 += 256) ls[t0] = 0.0f;
  __syncthreads();
  int lane = threadIdx.x & 63;
  int gw = (int)((blockIdx.x*256 + threadIdx.x) >> 6);
  int nw = (int)(gridDim.x * 4);
  int c16 = lane & 15, kg = lane >> 4;

  // B fragments for all 4 col-tiles x K=128 (built once per wave; W is tiny & cached)
  short8v Bf[2][2][4];
  #pragma unroll
  for (int s = 0; s < 2; ++s)
    #pragma unroll
    for (int t = 0; t < 2; ++t)
      #pragma unroll
      for (int c = 0; c < 4; ++c){
        short8v f;
        #pragma unroll
        for (int r = 0; r < 8; ++r){
          int k = s*64 + t*32 + kg*8 + r;
          f[r] = (short)f2bf(W[k*DIM + c*16 + c16]);
        }
        Bf[s][t][c] = f;
      }
  float bc[4];
  #pragma unroll
  for (int c = 0; c < 4; ++c) bc[c] = bias[c*16 + c16];

  float ssum[4] = {0,0,0,0}, ssq[4] = {0,0,0,0};
  const int ntile = RN/16;
  for (int tile = gw; tile < ntile; tile += nw){
    int r0 = tile*16;
    int ar = r0 + c16;                               // A row for this lane
    short8v A00 = ((const short8v*)Xd)[ar*8 + kg];       // k 0..31
    short8v A01 = ((const short8v*)Xd)[ar*8 + 4 + kg];   // k 32..63
    short8v A10 = ((const short8v*)Ag)[ar*8 + kg];
    short8v A11 = ((const short8v*)Ag)[ar*8 + 4 + kg];
    f32x4 acc[4];
    #pragma unroll
    for (int c = 0; c < 4; ++c){ f32x4 z = {bc[c],bc[c],bc[c],bc[c]}; acc[c] = z; }
    #pragma unroll
    for (int c = 0; c < 4; ++c){
      acc[c] = __builtin_amdgcn_mfma_f32_16x16x32_bf16(A00, Bf[0][0][c], acc[c], 0, 0, 0);
      acc[c] = __builtin_amdgcn_mfma_f32_16x16x32_bf16(A01, Bf[0][1][c], acc[c], 0, 0, 0);
      acc[c] = __builtin_amdgcn_mfma_f32_16x16x32_bf16(A10, Bf[1][0][c], acc[c], 0, 0, 0);
      acc[c] = __builtin_amdgcn_mfma_f32_16x16x32_bf16(A11, Bf[1][1][c], acc[c], 0, 0, 0);
    }
    int orow = r0 + kg*4;   // C layout: col = lane&15, row = (lane>>4)*4 + reg  [m89-verified]
    #pragma unroll
    for (int c = 0; c < 4; ++c)
      #pragma unroll
      for (int r = 0; r < 4; ++r){
        float v = acc[c][r];
        ssum[c] += v; ssq[c] += v*v;
        __builtin_nontemporal_store(f2bf(v), &Hout[(size_t)(orow + r)*DIM + c*16 + c16]);
      }
  }
  #pragma unroll
  for (int c = 0; c < 4; ++c){
    atomicAdd(&ls[c*16 + c16], ssum[c]);
    atomicAdd(&ls[64 + c*16 + c16], ssq[c]);
  }
  __syncthreads();
  for (int t0 = threadIdx.x; t0 < 128; t0 += 256) atomicAdd(&stats[t0], ls[t0]);
}

// ---- BN finalize: a = g*rsqrt(var+eps), c = be - mu*a ----
__global__ __launch_bounds__(64) void bnfin_k(const float* stats, const float* g,
                                              const float* be, float* ac){
  int j = threadIdx.x;
  if (j >= 64) return;
  float mu  = stats[j]    * (1.0f/RN);
  float var = stats[64+j] * (1.0f/RN) - mu*mu;
  float inv = rsqrtf(var + 1e-5f);
  float a = g[j] * inv;
  ac[j] = a;
  ac[64+j] = be[j] - mu*a;
}

// ---- BN + SiLU, in-place on internal bf16 buffer (layer 1) ----
__global__ __launch_bounds__(256) void bnapply_k(unsigned short* H, const float* __restrict__ ac, int n8){
  int i = blockIdx.x*256 + threadIdx.x;
  if (i >= n8) return;
  us8 v = ((us8*)H)[i];
  int cb = (i*8) & 63;
  #pragma unroll
  for (int r = 0; r < 8; ++r){
    float x = bf2f(v[r]);
    float y = ac[cb+r]*x + ac[64+cb+r];
    float o = y / (1.0f + expf(-y));
    v[r] = f2bf(o);
  }
  __builtin_nontemporal_store(v, (us8*)H + i);
}

// ---- BN + SiLU to d_out (dtype per flag) ----
__global__ __launch_bounds__(256) void bnout_k(const unsigned short* __restrict__ H,
                                               const float* __restrict__ ac,
                                               void* out, long long ooff,
                                               const int* __restrict__ flags, int n8){
  int i = blockIdx.x*256 + threadIdx.x;
  if (i >= n8) return;
  us8 v = ((const us8*)H)[i];
  int cb = (i*8) & 63;
  float o[8];
  #pragma unroll
  for (int r = 0; r < 8; ++r){
    float x = bf2f(v[r]);
    float y = ac[cb+r]*x + ac[64+cb+r];
    o[r] = y / (1.0f + expf(-y));
  }
  if (flags[0]){
    unsigned short* ob = (unsigned short*)out + ooff + (long long)i*8;
    us8 w;
    #pragma unroll
    for (int r = 0; r < 8; ++r) w[r] = f2bf(o[r]);
    __builtin_nontemporal_store(w, (us8*)ob);
  } else {
    float* ob = (float*)out + ooff + (long long)i*8;
    f32x4 w0 = {o[0],o[1],o[2],o[3]}, w1 = {o[4],o[5],o[6],o[7]};
    __builtin_nontemporal_store(w0, (f32x4*)ob);
    __builtin_nontemporal_store(w1, (f32x4*)ob + 1);
  }
}

extern "C" void kernel_launch(void* const* d_in, const int* in_sizes, int n_in,
                              void* d_out, int out_size, void* d_ws, size_t ws_size,
                              hipStream_t stream){
  (void)in_sizes; (void)n_in; (void)out_size;
  const void* user_emb = d_in[0];
  const void* item_emb = d_in[1];
  const void* go_src   = d_in[18];
  const void* go_dst   = d_in[19];
  const void* back_src = d_in[20];
  const void* back_dst = d_in[21];

  char* ws = (char*)d_ws;
  size_t off = 0;
  auto alloc = [&](size_t bytes) -> void* {
    void* p = ws + off;
    off += (bytes + 255) & ~((size_t)255);
    return p;
  };
  int*   flags  = (int*)  alloc(64);
  float* params = (float*)alloc((size_t)49920*4);
  float* bnac   = (float*)alloc(512*4);
  int*   bsum   = (int*)  alloc(1024*4);
  int*   cur2   = (int*)  alloc((size_t)NR2*4);   // 1.6MB, 256B-multiple -> stats contiguous
  float* stats  = (float*)alloc(512*4);
  int*   rs_all = (int*)  alloc((size_t)(NR2+1)*4);
  int*   col_all= (int*)  alloc((size_t)2*NE*4);
  unsigned short* user_bf = (unsigned short*)alloc((size_t)RN*DIM*2);
  unsigned short* item_bf = (unsigned short*)alloc((size_t)RN*DIM*2);
  unsigned short* x2u     = (unsigned short*)alloc((size_t)RN*DIM*2);
  unsigned short* x2i     = (unsigned short*)alloc((size_t)RN*DIM*2);
  unsigned short* agg     = (unsigned short*)alloc((size_t)RN*DIM*2);
  if (off > ws_size) return;  // ws too small: visible as absmax == 5.8125

  int* rs_go = rs_all;
  int* rs_bk = rs_all + RN;   // back rows' ranges live at col_all[1M..2M)

  const int GE  = (NE + 255)/256;          // 3907
  const int G8  = (RN*DIM/8)/256;          // 6250
  const int GS  = RN*64/256;               // 50000: one wave per row
  const int GSC = (NR2 + 511)/512;         // 782 scan blocks

  float* W_go1 = params + 0;     float* b_go1 = params + 12288;
  float* W_bk1 = params + 12352; float* b_bk1 = params + 24640;
  float* W_go2 = params + 24704; float* b_go2 = params + 36992;
  float* W_bk2 = params + 37056; float* b_bk2 = params + 49344;
  float* g1u = params + 49408; float* be1u = params + 49472;
  float* g1i = params + 49536; float* be1i = params + 49600;
  float* g2u = params + 49664; float* be2u = params + 49728;
  float* g2i = params + 49792; float* be2i = params + 49856;

  detect_k<<<1,256,0,stream>>>((const unsigned short*)user_emb, (const unsigned int*)go_src, flags);
  zero_k<<<(NR2+512+255)/256,256,0,stream>>>(cur2, NR2 + 512);   // cur2 + stats in one pass
  Ptrs16 ps;
  for (int i = 0; i < 16; ++i) ps.p[i] = d_in[2+i];
  conv_params_k<<<196,256,0,stream>>>(ps, flags, params);
  conv_emb_k<<<G8,256,0,stream>>>(user_emb, user_bf, flags, RN*DIM/8);
  conv_emb_k<<<G8,256,0,stream>>>(item_emb, item_bf, flags, RN*DIM/8);

  // CSR for both relations (concatenated scan: rows 0..RN are go-dst(items),
  // rows RN..2RN are back-dst(users); back col ranges start at 1M)
  count2_k<<<GE,256,0,stream>>>((const unsigned int*)go_dst, (const unsigned int*)back_dst, cur2, flags);
  scanA_k<<<GSC,512,0,stream>>>(cur2, bsum);
  scanB_k<<<1,1024,0,stream>>>(bsum, GSC, rs_all);
  scanC_k<<<GSC,512,0,stream>>>(cur2, bsum, rs_all, cur2);
  fill2_k<<<GE,256,0,stream>>>((const unsigned int*)go_src, (const unsigned int*)go_dst,
                               (const unsigned int*)back_src, (const unsigned int*)back_dst,
                               cur2, col_all, flags);

  // ---- layer 1 ----
  spmm_k<<<GS,256,0,stream>>>(rs_go, col_all, user_bf, agg);
  gemm_k<<<1024,256,0,stream>>>(item_bf, agg, W_go1, b_go1, x2i, stats + 0);
  bnfin_k<<<1,64,0,stream>>>(stats + 0, g1i, be1i, bnac + 0);
  bnapply_k<<<G8,256,0,stream>>>(x2i, bnac + 0, RN*DIM/8);

  spmm_k<<<GS,256,0,stream>>>(rs_bk, col_all, item_bf, agg);
  gemm_k<<<1024,256,0,stream>>>(user_bf, agg, W_bk1, b_bk1, x2u, stats + 128);
  bnfin_k<<<1,64,0,stream>>>(stats + 128, g1u, be1u, bnac + 128);
  bnapply_k<<<G8,256,0,stream>>>(x2u, bnac + 128, RN*DIM/8);

  // ---- layer 2 (GEMMs write in-place into agg; items first, then users) ----
  spmm_k<<<GS,256,0,stream>>>(rs_go, col_all, x2u, agg);
  gemm_k<<<1024,256,0,stream>>>(x2i, agg, W_go2, b_go2, agg, stats + 256);
  bnfin_k<<<1,64,0,stream>>>(stats + 256, g2i, be2i, bnac + 256);
  bnout_k<<<G8,256,0,stream>>>(agg, bnac + 256, d_out, (long long)RN*DIM, flags, RN*DIM/8);

  spmm_k<<<GS,256,0,stream>>>(rs_bk, col_all, x2i, agg);
  gemm_k<<<1024,256,0,stream>>>(x2u, agg, W_bk2, b_bk2, agg, stats + 384);
  bnfin_k<<<1,64,0,stream>>>(stats + 384, g2u, be2u, bnac + 384);
  bnout_k<<<G8,256,0,stream>>>(agg, bnac + 384, d_out, 0LL, flags, RN*DIM/8);
}